// Round 6
// baseline (743.698 us; speedup 1.0000x reference)
//
#include <hip/hip_runtime.h>

typedef short s16x8 __attribute__((ext_vector_type(8)));
typedef float f32x4 __attribute__((ext_vector_type(4)));

#define N_SAMPLES 65536
#define DIM 768
#define HID 384
#define NEXP 8
#define NCLS 8
#define JT 24   // HID/16
#define KT 24   // DIM/32

// workspace layout (bytes)
#define WS_CNT    0
#define WS_BUCKET 1024
#define WS_W1F    (WS_BUCKET + NEXP * N_SAMPLES * 4)     // 2,098,176
#define WS_W2T    (WS_W1F + NEXP * JT * KT * 64 * 8 * 2) // 6,816,768
// + NEXP*16*HID*2 = 98,304 -> total 6,915,072 (~6.9 MB)

// RNE bf16 (prep only)
__device__ __forceinline__ unsigned short f2bf(float f) {
  union { float f; unsigned u; } v; v.f = f;
  unsigned r = v.u + 0x7fffu + ((v.u >> 16) & 1u);
  return (unsigned short)(r >> 16);
}

// fast half-up pair: 2x v_add + 1x v_perm = 1.5 VALU/element
__device__ __forceinline__ unsigned cvt2(float a, float b) {
  union { float f; unsigned u; } ua, ub;
  ua.f = a; ub.f = b;
  return __builtin_amdgcn_perm(ub.u + 0x8000u, ua.u + 0x8000u, 0x07060302u);
}

// W1[e][k=768][j=384] f32 -> W1F in MFMA A-fragment order:
// W1F[((e*JT+jt)*KT+kt)*64 + lane][i] = W1[e][kt*32+(lane>>4)*8+i][jt*16+(lane&15)]
__global__ void k_w1frag(const float* __restrict__ W1,
                         unsigned short* __restrict__ W1F,
                         int* __restrict__ cnt) {
  if (blockIdx.x == 0 && blockIdx.y == 0 && threadIdx.x < NEXP)
    cnt[threadIdx.x] = 0;
  const int e = blockIdx.x;
  const int unit = blockIdx.y * 4 + (threadIdx.x >> 6);   // (jt,kt) flat
  const int lane = threadIdx.x & 63;
  const int jt = unit / KT, kt = unit % KT;
  const int j = jt * 16 + (lane & 15);
  const int k0 = kt * 32 + (lane >> 4) * 8;
  const float* src = W1 + ((size_t)e * DIM + k0) * HID + j;
  s16x8 v;
#pragma unroll
  for (int i = 0; i < 8; ++i) v[i] = (short)f2bf(src[(size_t)i * HID]);
  *(s16x8*)&W1F[(((size_t)e * JT * KT + unit) * 64 + lane) * 8] = v;
}

// blocks 0..255: bucket rows by expert
// blocks 256..263: W2[e][j][c] -> W2T[e][c(16, rows 8..15 zero)][j=384] bf16
__global__ void k_scatter(const int* __restrict__ qt, const float* __restrict__ W2,
                          int* __restrict__ cnt, int* __restrict__ bucket,
                          unsigned short* __restrict__ W2T) {
  const int t = threadIdx.x;
  if (blockIdx.x >= 256) {
    const int e = blockIdx.x - 256;
    for (int j = t; j < HID; j += 256) {
#pragma unroll
      for (int c = 0; c < NCLS; ++c)
        W2T[((size_t)e * 16 + c) * HID + j] = f2bf(W2[((size_t)e * HID + j) * NCLS + c]);
#pragma unroll
      for (int c = NCLS; c < 16; ++c) W2T[((size_t)e * 16 + c) * HID + j] = 0;
    }
    return;
  }
  __shared__ int lcnt[NEXP], lbase[NEXP];
  const int i = blockIdx.x * 256 + t;
  if (t < NEXP) lcnt[t] = 0;
  __syncthreads();
  const int e = qt[i];
  const int rank = atomicAdd(&lcnt[e], 1);
  __syncthreads();
  if (t < NEXP) lbase[t] = atomicAdd(&cnt[t], lcnt[t]);
  __syncthreads();
  bucket[(size_t)e * N_SAMPLES + lbase[e] + rank] = i;
}

// ---- gemm helper macros ----
// x super-step load: thread t covers row (t>>2), one full 128B line chunk (t&3).
// Each wave instruction touches exactly 16 fully-used cache lines.
#define XS(KB)                                                            \
  _Pragma("unroll") for (int w = 0; w < 8; ++w)                           \
      xs[w] = ((const float4*)(ap + (KB) * 128))[w];

// cvt 32 floats -> 32 bf16 shorts -> 4x ds_write_b128 into As[64][132]
#define ASTAGE(BUF)                                                       \
  _Pragma("unroll") for (int w = 0; w < 4; ++w) {                         \
    uint4 pk_ = {cvt2(xs[2*w].x, xs[2*w].y),   cvt2(xs[2*w].z, xs[2*w].w),\
                 cvt2(xs[2*w+1].x, xs[2*w+1].y), cvt2(xs[2*w+1].z, xs[2*w+1].w)}; \
    *(uint4*)&(BUF)[ar * 132 + ac * 32 + w * 8] = pk_;                    \
  }

// 6 coalesced b128 W1F fragment loads for k-step KS into rotation slot S
#define WLOAD(S, KS)                                                      \
  _Pragma("unroll") for (int ni = 0; ni < 6; ++ni)                        \
      wf[S][ni] = *(const s16x8*)(wfbase + ((size_t)ni * KT + (KS)) * 512);

// 4 ds_read_b128 x-frags (2-way free) + 24 MFMA (W = A-operand, x = B-operand)
#define COMPUTE(AS, L, S)                                                 \
  _Pragma("unroll") for (int mi = 0; mi < 4; ++mi) {                      \
    s16x8 xfr = *(const s16x8*)&(AS)[(mi * 16 + lrow) * 132 + (L) * 32 + quad * 8]; \
    _Pragma("unroll") for (int ni = 0; ni < 6; ++ni)                      \
        acc[mi][ni] = __builtin_amdgcn_mfma_f32_16x16x32_bf16(            \
            wf[S][ni], xfr, acc[mi][ni], 0, 0, 0);                        \
  }

// block = (expert e -> pinned XCD, one 64-row tile (y=160: ~1 tile/block), all 384 H)
// x: LDS super-steps (BK=128, 1 barrier per 4 k-steps, full-line staging map)
// W1F: register prefetch, distance 2 k-steps (3-slot rotation)
__global__ __launch_bounds__(256, 2) void k_moe_gemm(
    const float* __restrict__ x, const unsigned short* __restrict__ W1F,
    const float* __restrict__ b1, const unsigned short* __restrict__ W2T,
    const float* __restrict__ b2, const int* __restrict__ cnt,
    const int* __restrict__ bucket, float* __restrict__ out) {
  // region = Hs[64][392] (50,176 B); As dbuf 2x[64][132] (33,792 B) aliases it
  __shared__ __align__(16) short smem[25088];
  short* As0 = smem;
  short* As1 = smem + 8448;
  short* Hs  = smem;

  const int e = blockIdx.x;
  const int n_e = cnt[e];
  const int t = threadIdx.x;
  const int lane = t & 63;
  const int wave = t >> 6;
  const int lrow = lane & 15;
  const int quad = lane >> 4;
  const int ar = t >> 2;        // x staging row (0..63)
  const int ac = t & 3;         // x staging 128B chunk

  const unsigned short* wfbase =
      W1F + ((size_t)(e * JT + wave * 6) * KT) * 512 + lane * 8;

  for (int rt = blockIdx.y; rt * 64 < n_e; rt += gridDim.y) {
    const int row0 = rt * 64;
    __syncthreads();   // prev tile's epi-2 Hs reads done (no-op for 1-tile blocks)
    int slot = row0 + ar;
    if (slot >= n_e) slot = n_e - 1;       // clamp: dup compute, masked store
    const float* ap = x + (size_t)bucket[(size_t)e * N_SAMPLES + slot] * DIM + ac * 32;

    f32x4 acc[4][6];
#pragma unroll
    for (int mi = 0; mi < 4; ++mi)
#pragma unroll
      for (int ni = 0; ni < 6; ++ni) acc[mi][ni] = (f32x4){0.f, 0.f, 0.f, 0.f};

    float4 xs[8];
    s16x8 wf[3][6];
    XS(0)
    WLOAD(0, 0) WLOAD(1, 1)    // warm wf pipeline while x loads fly
    ASTAGE(As0)
    __syncthreads();

#pragma unroll
    for (int kb = 0; kb < 6; ++kb) {
      short* cur = (kb & 1) ? As1 : As0;
      short* nxt = (kb & 1) ? As0 : As1;
      if (kb < 5) XS(kb + 1)                 // full super-step of latency cover
#pragma unroll
      for (int l = 0; l < 4; ++l) {
        const int ks = kb * 4 + l;
        if (ks + 2 < 24) WLOAD((ks + 2) % 3, ks + 2)
        COMPUTE(cur, l, ks % 3)
      }
      if (kb < 5) ASTAGE(nxt)
      __syncthreads();                       // 1 barrier per 4 k-steps
    }

    // epilogue 1: bias+relu -> Hs[m][j]; acc: col(lane&15)=m, rows(quad*4+r)=j
#pragma unroll
    for (int ni = 0; ni < 6; ++ni) {
      const float4 bb = *(const float4*)(b1 + e * HID + wave * 96 + ni * 16 + quad * 4);
#pragma unroll
      for (int mi = 0; mi < 4; ++mi) {
        float v0 = acc[mi][ni][0] + bb.x; v0 = v0 > 0.f ? v0 : 0.f;
        float v1 = acc[mi][ni][1] + bb.y; v1 = v1 > 0.f ? v1 : 0.f;
        float v2 = acc[mi][ni][2] + bb.z; v2 = v2 > 0.f ? v2 : 0.f;
        float v3 = acc[mi][ni][3] + bb.w; v3 = v3 > 0.f ? v3 : 0.f;
        uint2 pk = {cvt2(v0, v1), cvt2(v2, v3)};
        *(uint2*)&Hs[(mi * 16 + lrow) * 392 + wave * 96 + ni * 16 + quad * 4] = pk;
      }
    }
    __syncthreads();

    // epilogue 2: layer-2 MFMA, M=64 (m-tile = wave), N=16 (8 valid), K=384
    {
      f32x4 acc2 = (f32x4){0.f, 0.f, 0.f, 0.f};
      const unsigned short* w2p = W2T + ((size_t)e * 16 + lrow) * HID + quad * 8;
#pragma unroll
      for (int kk = 0; kk < 12; ++kk) {
        s16x8 af = *(const s16x8*)&Hs[(wave * 16 + lrow) * 392 + kk * 32 + quad * 8];
        s16x8 bf = *(const s16x8*)(w2p + kk * 32);
        acc2 = __builtin_amdgcn_mfma_f32_16x16x32_bf16(af, bf, acc2, 0, 0, 0);
      }
      if (lrow < NCLS) {
        const float bb = b2[e * NCLS + lrow];
#pragma unroll
        for (int r = 0; r < 4; ++r) {
          const int m = wave * 16 + quad * 4 + r;
          if (row0 + m < n_e) {
            const int oi = bucket[(size_t)e * N_SAMPLES + row0 + m];
            out[(size_t)oi * NCLS + lrow] = acc2[r] + bb;
          }
        }
      }
    }
  }
}

extern "C" void kernel_launch(void* const* d_in, const int* in_sizes, int n_in,
                              void* d_out, int out_size, void* d_ws, size_t ws_size,
                              hipStream_t stream) {
  const float* x  = (const float*)d_in[0];
  const float* W1 = (const float*)d_in[1];
  const float* b1 = (const float*)d_in[2];
  const float* W2 = (const float*)d_in[3];
  const float* b2 = (const float*)d_in[4];
  const int* qt   = (const int*)d_in[5];
  float* out = (float*)d_out;
  char* ws = (char*)d_ws;

  int* cnt = (int*)(ws + WS_CNT);
  int* bucket = (int*)(ws + WS_BUCKET);
  unsigned short* W1F = (unsigned short*)(ws + WS_W1F);
  unsigned short* W2T = (unsigned short*)(ws + WS_W2T);

  k_w1frag<<<dim3(8, 144), dim3(256), 0, stream>>>(W1, W1F, cnt);
  k_scatter<<<dim3(264), dim3(256), 0, stream>>>(qt, W2, cnt, bucket, W2T);
  // y=160: ~129 active single-tile blocks per expert -> 1.02x load balance
  k_moe_gemm<<<dim3(8, 160), dim3(256), 0, stream>>>(x, W1F, b1, W2T, b2, cnt, bucket, out);
}